// Round 5
// baseline (1276.567 us; speedup 1.0000x reference)
//
#include <hip/hip_runtime.h>
#include <math.h>

#define DEV __device__ __forceinline__

typedef short short8 __attribute__((ext_vector_type(8)));
typedef float float4v __attribute__((ext_vector_type(4)));

// round-to-nearest-even fp32 -> bf16 (values here are finite; no NaN path)
DEV unsigned short f2bf(float f) {
    union { float f; unsigned u; } v; v.f = f;
    unsigned r = v.u + 0x7FFFu + ((v.u >> 16) & 1u);
    return (unsigned short)(r >> 16);
}

// async global->LDS, 16B per lane; LDS dest must be wave-uniform base (+lane*16)
DEV void async16(const unsigned short* g, unsigned short* l) {
    __builtin_amdgcn_global_load_lds(
        (const __attribute__((address_space(1))) unsigned int*)g,
        (__attribute__((address_space(3))) unsigned int*)l, 16, 0, 0);
}

// block-wide reduction (256 threads). mode 0 = sum, 1 = max.
DEV float block_reduce(float v, int mode) {
    #pragma unroll
    for (int off = 32; off; off >>= 1) {
        float o = __shfl_xor(v, off);
        v = mode ? fmaxf(v, o) : (v + o);
    }
    __shared__ float sbuf[4];
    __syncthreads();
    if ((threadIdx.x & 63) == 0) sbuf[threadIdx.x >> 6] = v;
    __syncthreads();
    float r = sbuf[0];
    #pragma unroll
    for (int w = 1; w < 4; w++) r = mode ? fmaxf(r, sbuf[w]) : (r + sbuf[w]);
    return r;
}

// ---------------------------------------------------------------------------
// bf16 MFMA GEMM: C[M,N] = A[M,K] @ Wt[N,K]^T (+bias)(+=Cf)(GELU)
// m97 structure: 128x128 tile, BK=32, linear LDS [row][32], staging via
// global_load_lds width=16 (4 issues/wave/K-step), 2 barriers per K-step.
// 3-way split bias (fused N-concat projections). Cb has its own pitch Nb
// (lets bf16 output land inside a wider concat slab).
// ---------------------------------------------------------------------------
template <bool BIAS, bool ACCUM, bool GELU>
__global__ __launch_bounds__(256) void gemm_bf16_kernel(
    const unsigned short* __restrict__ A, int lda,
    const unsigned short* __restrict__ Bt, int ldb,
    const float* __restrict__ bias, const float* __restrict__ bias2,
    const float* __restrict__ bias3, int ns1, int ns2,
    float* __restrict__ Cf, unsigned short* __restrict__ Cb,
    int N, int Nb, int K)
{
    __shared__ unsigned short As[128 * 32];   // linear: row*32 + k  (no pad)
    __shared__ unsigned short Bs[128 * 32];
    const int tid = threadIdx.x;
    const int w = tid >> 6, lane = tid & 63;
    const int l15 = lane & 15, quad = lane >> 4;
    const int m0 = blockIdx.y * 128, n0 = blockIdx.x * 128;
    const int wm = (w >> 1) * 64, wn = (w & 1) * 64;
    const int lr = lane >> 2, lc = (lane & 3) * 8;  // lane -> (row-in-16, k-chunk)

    float4v acc[4][4];
    #pragma unroll
    for (int i = 0; i < 4; i++)
        #pragma unroll
        for (int j = 0; j < 4; j++) acc[i][j] = (float4v){0.f, 0.f, 0.f, 0.f};

    const unsigned short* Ab = A  + (size_t)(m0 + w * 16 + lr) * lda + lc;
    const unsigned short* Bb = Bt + (size_t)(n0 + w * 16 + lr) * ldb + lc;
    unsigned short* AsW = As + (w * 16) * 32;
    unsigned short* BsW = Bs + (w * 16) * 32;

    for (int k0 = 0; k0 < K; k0 += 32) {
        __syncthreads();                       // prior reads done before overwrite
        async16(Ab + k0, AsW);
        async16(Ab + (size_t)64 * lda + k0, AsW + 64 * 32);
        async16(Bb + k0, BsW);
        async16(Bb + (size_t)64 * ldb + k0, BsW + 64 * 32);
        __syncthreads();                       // compiler drains vmcnt here
        short8 Af[4], Bf[4];
        #pragma unroll
        for (int mt = 0; mt < 4; mt++)
            Af[mt] = *(const short8*)(As + (wm + mt * 16 + l15) * 32 + quad * 8);
        #pragma unroll
        for (int nt = 0; nt < 4; nt++)
            Bf[nt] = *(const short8*)(Bs + (wn + nt * 16 + l15) * 32 + quad * 8);
        #pragma unroll
        for (int mt = 0; mt < 4; mt++)
            #pragma unroll
            for (int nt = 0; nt < 4; nt++)
                acc[mt][nt] = __builtin_amdgcn_mfma_f32_16x16x32_bf16(
                    Af[mt], Bf[nt], acc[mt][nt], 0, 0, 0);
    }

    #pragma unroll
    for (int nt = 0; nt < 4; nt++) {
        const int n = n0 + wn + nt * 16 + l15;
        float bv = 0.f;
        if (BIAS) bv = (n < ns1) ? bias[n] : (n < ns2) ? bias2[n - ns1]
                                                       : bias3[n - ns2];
        #pragma unroll
        for (int mt = 0; mt < 4; mt++) {
            #pragma unroll
            for (int r = 0; r < 4; r++) {
                const int m = m0 + wm + mt * 16 + quad * 4 + r;
                const size_t off = (size_t)m * N + n;
                float v = acc[mt][nt][r] + bv;
                if (ACCUM) v += Cf[off];
                if (GELU) v = 0.5f * v * (1.f + erff(v * 0.70710678118654752f));
                if (Cf) Cf[off] = v;
                if (Cb) Cb[(size_t)m * Nb + n] = f2bf(v);
            }
        }
    }
}

// ---------------------------------------------------------------------------
// Weight transpose+cast: W fp32 [K][N] -> Wt bf16 [N][K]
// ---------------------------------------------------------------------------
__global__ __launch_bounds__(256) void wtrans_kernel(
    const float* __restrict__ W, unsigned short* __restrict__ Wt, int K, int N)
{
    __shared__ float t[32][33];
    const int n0 = blockIdx.x * 32, k0 = blockIdx.y * 32;
    const int c = threadIdx.x & 31, r8 = threadIdx.x >> 5;
    #pragma unroll
    for (int i = 0; i < 4; i++) {
        const int r = r8 + i * 8;
        t[r][c] = W[(size_t)(k0 + r) * N + n0 + c];
    }
    __syncthreads();
    #pragma unroll
    for (int i = 0; i < 4; i++) {
        const int r = r8 + i * 8;
        Wt[(size_t)(n0 + r) * K + k0 + c] = f2bf(t[c][r]);
    }
}

// bf16 transpose per batch: in [b][R][vpitch] cols [voff,voff+C) -> out [b][C][R]
__global__ __launch_bounds__(256) void trans_kernel(
    const unsigned short* __restrict__ v, unsigned short* __restrict__ Vt,
    int R, int C, int vpitch, int voff)
{
    __shared__ unsigned short t[32][33];
    const int b = blockIdx.z, r0 = blockIdx.x * 32, c0 = blockIdx.y * 32;
    const int c = threadIdx.x & 31, r8 = threadIdx.x >> 5;
    #pragma unroll
    for (int i = 0; i < 4; i++) {
        const int r = r8 + i * 8;
        t[r][c] = v[((size_t)b * R + r0 + r) * vpitch + voff + c0 + c];
    }
    __syncthreads();
    #pragma unroll
    for (int i = 0; i < 4; i++) {
        const int r = r8 + i * 8;
        Vt[((size_t)b * C + c0 + r) * R + r0 + c] = t[c][r];
    }
}

// fp32 -> bf16 elementwise (count = grid*256*4)
__global__ __launch_bounds__(256) void castbf_kernel(
    const float* __restrict__ x, unsigned short* __restrict__ y)
{
    const size_t i = ((size_t)blockIdx.x * 256 + threadIdx.x) * 4;
    float4 v = *(const float4*)(x + i);
    ushort4 o;
    o.x = f2bf(v.x); o.y = f2bf(v.y); o.z = f2bf(v.z); o.w = f2bf(v.w);
    *(ushort4*)(y + i) = o;
}

// pack a 0/1 fp32 mask into bits: bit i of word w = (x[32w+i] > 0.5)
__global__ __launch_bounds__(256) void packmask_kernel(
    const float* __restrict__ x, unsigned int* __restrict__ bits)
{
    const size_t idx = (size_t)blockIdx.x * 256 + threadIdx.x;
    const unsigned long long m = __ballot(x[idx] > 0.5f);
    const int lane = threadIdx.x & 63;
    if (lane == 0)  bits[idx >> 5] = (unsigned)m;
    if (lane == 32) bits[idx >> 5] = (unsigned)(m >> 32);
}

// ---------------------------------------------------------------------------
// LayerNorm over 1024 cols; optional residuals; fp32 and/or bf16 outputs.
// outb has its own row pitch (base_b) so bf16 can land in a concat slab.
// ---------------------------------------------------------------------------
DEV void ln_finish(float4 xv, const float* __restrict__ g,
                   const float* __restrict__ bb, float* __restrict__ outf,
                   unsigned short* __restrict__ outb, size_t base_f, size_t base_b)
{
    float s  = xv.x + xv.y + xv.z + xv.w;
    float s2 = xv.x * xv.x + xv.y * xv.y + xv.z * xv.z + xv.w * xv.w;
    #pragma unroll
    for (int off = 32; off; off >>= 1) {
        s += __shfl_xor(s, off);
        s2 += __shfl_xor(s2, off);
    }
    __shared__ float sa[4], sb[4];
    if ((threadIdx.x & 63) == 0) {
        sa[threadIdx.x >> 6] = s; sb[threadIdx.x >> 6] = s2;
    }
    __syncthreads();
    s  = sa[0] + sa[1] + sa[2] + sa[3];
    s2 = sb[0] + sb[1] + sb[2] + sb[3];
    const float mu  = s * (1.f / 1024.f);
    const float var = fmaxf(s2 * (1.f / 1024.f) - mu * mu, 0.f);
    const float inv = rsqrtf(var + 1e-12f);
    const int tid = threadIdx.x;
    float4 gv = ((const float4*)g)[tid];
    float4 bv = ((const float4*)bb)[tid];
    float4 o;
    o.x = (xv.x - mu) * inv * gv.x + bv.x;
    o.y = (xv.y - mu) * inv * gv.y + bv.y;
    o.z = (xv.z - mu) * inv * gv.z + bv.z;
    o.w = (xv.w - mu) * inv * gv.w + bv.w;
    if (outf) ((float4*)(outf + base_f))[tid] = o;
    if (outb) {
        ushort4 ob;
        ob.x = f2bf(o.x); ob.y = f2bf(o.y); ob.z = f2bf(o.z); ob.w = f2bf(o.w);
        ((ushort4*)(outb + base_b))[tid] = ob;
    }
}

__global__ __launch_bounds__(256) void ln_kernel(
    const float* __restrict__ x, const float* __restrict__ r1,
    const float* __restrict__ r2, const float* __restrict__ g,
    const float* __restrict__ bb, float* __restrict__ outf,
    unsigned short* __restrict__ outb, int obp)
{
    const size_t base = (size_t)blockIdx.x * 1024;
    const size_t base_b = (size_t)blockIdx.x * obp;
    const int tid = threadIdx.x;
    float4 xv = ((const float4*)(x + base))[tid];
    if (r1) {
        float4 a = ((const float4*)(r1 + base))[tid];
        xv.x += a.x; xv.y += a.y; xv.z += a.z; xv.w += a.w;
    }
    if (r2) {
        float4 a = ((const float4*)(r2 + base))[tid];
        xv.x += a.x; xv.y += a.y; xv.z += a.z; xv.w += a.w;
    }
    ln_finish(xv, g, bb, outf, outb, base, base_b);
}

__global__ __launch_bounds__(256) void gate_ln_kernel(
    const float* __restrict__ gpre, const float* __restrict__ co,
    const float* __restrict__ gn, const float* __restrict__ g,
    const float* __restrict__ bb, float* __restrict__ outf,
    unsigned short* __restrict__ outb)
{
    const size_t base = (size_t)blockIdx.x * 1024;
    const int tid = threadIdx.x;
    float4 gp = ((const float4*)(gpre + base))[tid];
    float4 cv = ((const float4*)(co + base))[tid];
    float4 gv = ((const float4*)(gn + base))[tid];
    float4 xv; float s;
    s = 1.f / (1.f + __expf(-gp.x)); xv.x = s * cv.x + (1.f - s) * gv.x;
    s = 1.f / (1.f + __expf(-gp.y)); xv.y = s * cv.y + (1.f - s) * gv.y;
    s = 1.f / (1.f + __expf(-gp.z)); xv.z = s * cv.z + (1.f - s) * gv.z;
    s = 1.f / (1.f + __expf(-gp.w)); xv.w = s * cv.w + (1.f - s) * gv.w;
    ln_finish(xv, g, bb, outf, outb, base, base);
}

// ---------------------------------------------------------------------------
// MFMA flash attention + inline focal loss, v6: v5 structure + software
// double-buffer (T3 2-phase / T14 reg-staging): global loads for tile t+1
// are issued BEFORE computing tile t (VMEM latency hides under ~700cy of
// MFMA+softmax), ds_write lands in the alternate LDS buffer, ONE barrier
// per iteration. XCD swizzle keeps each (b,h)'s K/V in one XCD's L2.
// Fixed-max softmax (scores bounded; masked -> exp==0).
// Q/K from fused QKV gemm (pitch 2560 = q|k|v); q1/k1 fused (pitch 512).
// ---------------------------------------------------------------------------
__global__ __launch_bounds__(256) void attn_mfma_kernel(
    const unsigned short* __restrict__ qkv,  // [B*N,2560] bf16
    const unsigned short* __restrict__ q1k1, // [B*N,512]  bf16
    const unsigned short* __restrict__ Vt,   // [B*1024(d)][1024(m)] bf16
    const float* __restrict__ am,            // [B*N]
    const unsigned int* __restrict__ smb,    // packed smask bits [B,3,N,N/32]
    unsigned short* __restrict__ ctx,        // [B*N,1024] bf16
    float* __restrict__ nump, float* __restrict__ denp)
{
    // XCD swizzle: 512 blocks, 8 XCDs; each XCD owns 4 complete (b,h) groups.
    const int bid0 = blockIdx.x + 16 * blockIdx.y + 64 * blockIdx.z;
    const int xcd = bid0 & 7, s = bid0 >> 3;
    const int grp = xcd + 8 * (s >> 4);      // 0..31 = b*4 + h
    const int nb = s & 15;
    const int h = grp & 3, b = grp >> 2;
    const int tid = threadIdx.x;
    const int w = tid >> 6, lane = tid & 63;
    const int l15 = lane & 15, quad = lane >> 4;
    const int n0 = nb * 64;

    __shared__ unsigned short Ks[2][32 * 264];  // double-buffered, pitch 264
    __shared__ unsigned short Vs[2][256 * 40];  // [d][m] pitch 40
    __shared__ unsigned short Ps[4][16 * 40];   // per-wave P tile

    const unsigned short* qsrc; const unsigned short* ksrc; int pitch;
    if (h == 0) { qsrc = q1k1;                ksrc = q1k1 + 256;                pitch = 512; }
    else        { qsrc = qkv + (h - 1) * 256; ksrc = qkv + 768 + (h - 1) * 256; pitch = 2560; }

    // Q fragments directly from global (resident across the loop)
    short8 Qf[8];
    {
        const unsigned short* qrow =
            qsrc + (size_t)(b * 1024 + n0 + w * 16 + l15) * pitch;
        #pragma unroll
        for (int kk = 0; kk < 8; kk++)
            Qf[kk] = *(const short8*)(qrow + kk * 32 + quad * 8);
    }

    // staging descriptors: 4 K-chunks + 4 V-chunks of 16B per thread
    const unsigned short* kap[4]; int kofs[4];
    const unsigned short* vap[4]; int vofs[4];
    const int vrow0 = b * 1024 + h * 256;
    #pragma unroll
    for (int i = 0; i < 4; i++) {
        const int c = tid + i * 256;
        const int krow = c >> 5, kc = (c & 31) * 8;
        kap[i] = ksrc + (size_t)(b * 1024 + krow) * pitch + kc;
        kofs[i] = krow * 264 + kc;
        const int d = c >> 2, mc = (c & 3) * 8;
        vap[i] = Vt + (size_t)(vrow0 + d) * 1024 + mc;
        vofs[i] = d * 40 + mc;
    }

    float4v O[16];
    #pragma unroll
    for (int i = 0; i < 16; i++) O[i] = (float4v){0.f, 0.f, 0.f, 0.f};
    float lsum[4] = {0.f, 0.f, 0.f, 0.f};
    float flsum = 0.f, dencnt = 0.f;
    const int nrow_base = n0 + w * 16 + quad * 4;  // + r = this lane's rows
    const float* amrow = am + b * 1024;
    float amn[4];
    #pragma unroll
    for (int r = 0; r < 4; r++) amn[r] = amrow[nrow_base + r];
    const unsigned int* smw = (h > 0)
        ? smb + ((size_t)(b * 3 + (h - 1)) << 15) : nullptr;   // 1024*32 words

    // prologue: stage tile 0 into buffer 0
    uint4 kr[4], vr[4];
    #pragma unroll
    for (int i = 0; i < 4; i++) {
        kr[i] = *(const uint4*)kap[i]; kap[i] += (size_t)32 * pitch;
        vr[i] = *(const uint4*)vap[i]; vap[i] += 32;
    }
    #pragma unroll
    for (int i = 0; i < 4; i++) {
        *(uint4*)(&Ks[0][0] + kofs[i]) = kr[i];
        *(uint4*)(&Vs[0][0] + vofs[i]) = vr[i];
    }
    __syncthreads();
    int cur = 0;

    for (int m0 = 0; m0 < 1024; m0 += 32) {
        const bool more = (m0 + 32 < 1024);
        if (more) {                              // issue next-tile loads early
            #pragma unroll
            for (int i = 0; i < 4; i++) {
                kr[i] = *(const uint4*)kap[i]; kap[i] += (size_t)32 * pitch;
                vr[i] = *(const uint4*)vap[i]; vap[i] += 32;
            }
        }
        const unsigned short* Ksc = &Ks[cur][0];
        const unsigned short* Vsc = &Vs[cur][0];

        // S = Q K^T (16 x 32 per wave)
        float4v S[2];
        #pragma unroll
        for (int st = 0; st < 2; st++) {
            float4v a = (float4v){0.f, 0.f, 0.f, 0.f};
            #pragma unroll
            for (int kk = 0; kk < 8; kk++) {
                short8 Kf = *(const short8*)(Ksc + (st * 16 + l15) * 264 + kk * 32 + quad * 8);
                a = __builtin_amdgcn_mfma_f32_16x16x32_bf16(Qf[kk], Kf, a, 0, 0, 0);
            }
            S[st] = a;
        }

        // packed structure-mask words: one per q-row, covers cols [m0,m0+32)
        unsigned int wb[4];
        if (h > 0) {
            #pragma unroll
            for (int r = 0; r < 4; r++)
                wb[r] = smw[(size_t)(nrow_base + r) * 32 + (m0 >> 5)];
        }

        // masks, focal loss, exp (fixed-max softmax)
        float e[2][4];
        #pragma unroll
        for (int st = 0; st < 2; st++) {
            const int mcol = m0 + st * 16 + l15;
            const float amm = amrow[mcol];
            const float am0 = (1.f - amm) * (-10000.f);
            #pragma unroll
            for (int r = 0; r < 4; r++) {
                const float sraw = S[st][r];
                float scv;
                if (h > 0) {
                    const float t = (float)((wb[r] >> (st * 16 + l15)) & 1u);
                    const int nrow = nrow_base + r;
                    const float s3 = sraw + am0;
                    const float idxw =
                        ((amn[r] * amm * ((mcol == nrow) ? 0.f : 1.f)) > 0.5f) ? 1.f : 0.f;
                    // shared-transcendental focal loss:
                    // E=exp(-|s3|); softplus(s3)=max(s3,0)+log(1+E);
                    // p=sigmoid(s3)=(s3>=0 ? 1 : E)/(1+E);
                    // -log_sigmoid(s3)=softplus(-s3)=softplus(s3)-s3
                    const float E = __expf(-fabsf(s3));
                    const float L = __logf(1.f + E);
                    const float R = 1.f / (1.f + E);
                    const float p = (s3 >= 0.f) ? R : E * R;
                    const float sp = fmaxf(s3, 0.f) + L;      // softplus(s3)
                    const float omp = 1.f - p;
                    flsum += idxw * (0.25f * t * omp * omp * (sp - s3)
                                   + 0.75f * (1.f - t) * p * p * sp);
                    dencnt += idxw;
                    scv = sraw * 0.0625f + (1.f - t) * (-10000.f);
                } else {
                    scv = sraw * 0.0625f + am0;
                }
                const float ev = __expf(fminf(scv, 30.f));  // overflow guard
                e[st][r] = ev;
                lsum[r] += ev;
            }
        }

        // P: C-layout -> LDS -> A-layout (per-wave buffer; no barrier needed)
        #pragma unroll
        for (int st = 0; st < 2; st++)
            #pragma unroll
            for (int r = 0; r < 4; r++)
                Ps[w][(quad * 4 + r) * 40 + st * 16 + l15] = f2bf(e[st][r]);
        const short8 Pf = *(const short8*)(&Ps[w][l15 * 40 + quad * 8]);
        #pragma unroll
        for (int dt = 0; dt < 16; dt++) {
            short8 Vf = *(const short8*)(Vsc + (dt * 16 + l15) * 40 + quad * 8);
            O[dt] = __builtin_amdgcn_mfma_f32_16x16x32_bf16(Pf, Vf, O[dt], 0, 0, 0);
        }

        if (more) {                              // write next tile, one barrier
            unsigned short* Ksn = &Ks[cur ^ 1][0];
            unsigned short* Vsn = &Vs[cur ^ 1][0];
            #pragma unroll
            for (int i = 0; i < 4; i++) {
                *(uint4*)(Ksn + kofs[i]) = kr[i];
                *(uint4*)(Vsn + vofs[i]) = vr[i];
            }
            __syncthreads();
            cur ^= 1;
        }
    }

    // one row-sum reduction across the 16 col-lanes, then write out
    float rinv[4];
    #pragma unroll
    for (int r = 0; r < 4; r++) {
        float s2 = lsum[r];
        #pragma unroll
        for (int off = 8; off; off >>= 1) s2 += __shfl_xor(s2, off);
        rinv[r] = 1.f / s2;
    }
    #pragma unroll
    for (int dt = 0; dt < 16; dt++)
        #pragma unroll
        for (int r = 0; r < 4; r++)
            ctx[(size_t)(b * 1024 + nrow_base + r) * 1024 + h * 256 + dt * 16 + l15]
                = f2bf(O[dt][r] * rinv[r]);

    if (h > 0) {
        const float fb = block_reduce(flsum, 0);
        if (tid == 0) nump[(b * 3 + (h - 1)) * 16 + nb] = fb;
        if (h == 1) {
            const float db = block_reduce(dencnt, 0);
            if (tid == 0) denp[b * 16 + nb] = db;
        }
    }
}

// ---------------------------------------------------------------------------
// MFMA cross attention v6: staged + double-buffered + bit-packed mask + XCD
// swizzle. qk-dim 64, v-dim 256, M=512 keys.
// K from fused cK|cV gemm output (pitch 1280 = ck(256)|cv(1024)).
// ---------------------------------------------------------------------------
__global__ __launch_bounds__(256) void cross_mfma_kernel(
    const unsigned short* __restrict__ cq,   // [B*N, 256] bf16 (4 heads x 64)
    const unsigned short* __restrict__ ckv,  // [B*512, 1280] bf16
    const unsigned short* __restrict__ cvt,  // [B][1024(d)][512(m)] bf16
    const unsigned int* __restrict__ csmb,   // packed bits [B,N,512/32]
    unsigned short* __restrict__ cctx)       // [B*N, 1024] bf16
{
    const int bid0 = blockIdx.x + 16 * blockIdx.y + 64 * blockIdx.z;
    const int xcd = bid0 & 7, s = bid0 >> 3;
    const int grp = xcd + 8 * (s >> 4);
    const int nb = s & 15;
    const int h = grp & 3, b = grp >> 2;
    const int tid = threadIdx.x;
    const int w = tid >> 6, lane = tid & 63;
    const int l15 = lane & 15, quad = lane >> 4;
    const int n0 = nb * 64;

    __shared__ unsigned short Ks[2][32 * 72];
    __shared__ unsigned short Vs[2][256 * 40];  // [d][m] pitch 40
    __shared__ unsigned short Ps[4][16 * 40];

    short8 Qf[2];
    {
        const unsigned short* qrow =
            cq + (size_t)(b * 1024 + n0 + w * 16 + l15) * 256 + h * 64;
        #pragma unroll
        for (int kk = 0; kk < 2; kk++)
            Qf[kk] = *(const short8*)(qrow + kk * 32 + quad * 8);
    }

    // staging descriptors: 1 K-chunk + 4 V-chunks of 16B per thread
    const int vrow0 = b * 1024 + h * 256;
    const int krow = tid >> 3, kc = (tid & 7) * 8;
    const unsigned short* kap = ckv + (size_t)(b * 512 + krow) * 1280 + h * 64 + kc;
    const int kofs = krow * 72 + kc;
    const unsigned short* vap[4]; int vofs[4];
    #pragma unroll
    for (int i = 0; i < 4; i++) {
        const int c = tid + i * 256;
        const int d = c >> 2, mc = (c & 3) * 8;
        vap[i] = cvt + (size_t)(vrow0 + d) * 512 + mc;
        vofs[i] = d * 40 + mc;
    }

    float4v O[16];
    #pragma unroll
    for (int i = 0; i < 16; i++) O[i] = (float4v){0.f, 0.f, 0.f, 0.f};
    float lsum[4] = {0.f, 0.f, 0.f, 0.f};
    const int nrow_base = n0 + w * 16 + quad * 4;
    const unsigned int* csw = csmb + (size_t)(b * 1024) * 16;  // 16 words/row

    // prologue: stage tile 0 into buffer 0
    uint4 kr, vr[4];
    kr = *(const uint4*)kap; kap += (size_t)32 * 1280;
    #pragma unroll
    for (int i = 0; i < 4; i++) { vr[i] = *(const uint4*)vap[i]; vap[i] += 32; }
    *(uint4*)(&Ks[0][0] + kofs) = kr;
    #pragma unroll
    for (int i = 0; i < 4; i++) *(uint4*)(&Vs[0][0] + vofs[i]) = vr[i];
    __syncthreads();
    int cur = 0;

    for (int m0 = 0; m0 < 512; m0 += 32) {
        const bool more = (m0 + 32 < 512);
        if (more) {
            kr = *(const uint4*)kap; kap += (size_t)32 * 1280;
            #pragma unroll
            for (int i = 0; i < 4; i++) { vr[i] = *(const uint4*)vap[i]; vap[i] += 32; }
        }
        const unsigned short* Ksc = &Ks[cur][0];
        const unsigned short* Vsc = &Vs[cur][0];

        float4v S[2];
        #pragma unroll
        for (int st = 0; st < 2; st++) {
            float4v a = (float4v){0.f, 0.f, 0.f, 0.f};
            #pragma unroll
            for (int kk = 0; kk < 2; kk++) {
                short8 Kf = *(const short8*)(Ksc + (st * 16 + l15) * 72 + kk * 32 + quad * 8);
                a = __builtin_amdgcn_mfma_f32_16x16x32_bf16(Qf[kk], Kf, a, 0, 0, 0);
            }
            S[st] = a;
        }

        unsigned int wb[4];
        #pragma unroll
        for (int r = 0; r < 4; r++)
            wb[r] = csw[(size_t)(nrow_base + r) * 16 + (m0 >> 5)];

        float e[2][4];
        #pragma unroll
        for (int st = 0; st < 2; st++) {
            #pragma unroll
            for (int r = 0; r < 4; r++) {
                const float msk = (float)((wb[r] >> (st * 16 + l15)) & 1u);
                const float scv = S[st][r] * 0.125f + (1.f - msk) * (-10000.f);
                const float ev = __expf(fminf(scv, 30.f));
                e[st][r] = ev;
                lsum[r] += ev;
            }
        }

        #pragma unroll
        for (int st = 0; st < 2; st++)
            #pragma unroll
            for (int r = 0; r < 4; r++)
                Ps[w][(quad * 4 + r) * 40 + st * 16 + l15] = f2bf(e[st][r]);
        const short8 Pf = *(const short8*)(&Ps[w][l15 * 40 + quad * 8]);
        #pragma unroll
        for (int dt = 0; dt < 16; dt++) {
            short8 Vf = *(const short8*)(Vsc + (dt * 16 + l15) * 40 + quad * 8);
            O[dt] = __builtin_amdgcn_mfma_f32_16x16x32_bf16(Pf, Vf, O[dt], 0, 0, 0);
        }

        if (more) {
            unsigned short* Ksn = &Ks[cur ^ 1][0];
            unsigned short* Vsn = &Vs[cur ^ 1][0];
            *(uint4*)(Ksn + kofs) = kr;
            #pragma unroll
            for (int i = 0; i < 4; i++) *(uint4*)(Vsn + vofs[i]) = vr[i];
            __syncthreads();
            cur ^= 1;
        }
    }

    float rinv[4];
    #pragma unroll
    for (int r = 0; r < 4; r++) {
        float s2 = lsum[r];
        #pragma unroll
        for (int off = 8; off; off >>= 1) s2 += __shfl_xor(s2, off);
        rinv[r] = 1.f / s2;
    }
    #pragma unroll
    for (int dt = 0; dt < 16; dt++)
        #pragma unroll
        for (int r = 0; r < 4; r++)
            cctx[(size_t)(b * 1024 + nrow_base + r) * 1024 + h * 256 + dt * 16 + l15]
                = f2bf(O[dt][r] * rinv[r]);
}

// loss = sum(nump[384]) / (3 * sum(denp[128])), deterministic
__global__ __launch_bounds__(256) void loss_reduce_kernel(
    const float* __restrict__ nump, const float* __restrict__ denp,
    float* __restrict__ out)
{
    __shared__ double sn[256], sd[256];
    const int tid = threadIdx.x;
    double ns = 0.0, ds = 0.0;
    for (int i = tid; i < 384; i += 256) ns += (double)nump[i];
    for (int i = tid; i < 128; i += 256) ds += (double)denp[i];
    sn[tid] = ns; sd[tid] = ds;
    __syncthreads();
    for (int off = 128; off; off >>= 1) {
        if (tid < off) { sn[tid] += sn[tid + off]; sd[tid] += sd[tid + off]; }
        __syncthreads();
    }
    if (tid == 0) out[0] = (float)(sn[0] / (3.0 * sd[0]));
}

// ---------------------------------------------------------------------------
extern "C" void kernel_launch(void* const* d_in, const int* in_sizes, int n_in,
                              void* d_out, int out_size, void* d_ws, size_t ws_size,
                              hipStream_t stream)
{
    (void)in_sizes; (void)n_in; (void)out_size; (void)ws_size;
    const float* hs   = (const float*)d_in[0];
    const float* am   = (const float*)d_in[1];
    const float* smask= (const float*)d_in[2];
    const float* sent = (const float*)d_in[3];
    const float* ent  = (const float*)d_in[4];
    const float* csm  = (const float*)d_in[5];
    const float* enc  = (const float*)d_in[6];
    const float* Wq  = (const float*)d_in[8];  const float* bq  = (const float*)d_in[9];
    const float* Wk  = (const float*)d_in[10]; const float* bk  = (const float*)d_in[11];
    const float* Wv  = (const float*)d_in[12]; const float* bv  = (const float*)d_in[13];
    const float* Wq1 = (const float*)d_in[14]; const float* bq1 = (const float*)d_in[15];
    const float* Wk1 = (const float*)d_in[16]; const float* bk1 = (const float*)d_in[17];
    const float* ln_g= (const float*)d_in[18]; const float* ln_b= (const float*)d_in[19];
    const float* gW  = (const float*)d_in[20]; const float* gb  = (const float*)d_in[21];
    const float* gng = (const float*)d_in[22]; const float* gnb = (const float*)d_in[23];
    const float* cWq = (const float*)d_in[24]; const float* cbq = (const float*)d_in[25];
    const float* cWk = (const float*)d_in[26]; const float* cbk = (const float*)d_in[27];
    const float* cWv = (const float*)d_in[28]; const float* cbv = (const float*)d_in[29];
    const float* cWo = (const float*)d_in[30]; const float* cbo = (const float*)d_in[31];
    const float* cWg = (const float*)d_in[32]; const float* cbg = (const float*)d_in[33];
    const float* clg = (const float*)d_in[34]; const float* clb = (const float*)d_in[35];
    const float* oW1 = (const float*)d_in[36]; const float* ob1 = (const float*)d_in[37];
    const float* l1g = (const float*)d_in[38]; const float* l1b = (const float*)d_in[39];
    const float* oW2 = (const float*)d_in[40]; const float* ob2 = (const float*)d_in[41];
    const float* oW3 = (const float*)d_in[42]; const float* ob3 = (const float*)d_in[43];
    const float* l3g = (const float*)d_in[44]; const float* l3b = (const float*)d_in[45];
    float* out = (float*)d_out;

    typedef unsigned short ush;
    char* wsb = (char*)d_ws;
    // ---- weight-transpose arena (bf16); wq|wk|wv, wq1|wk1, cWk|cWv adjacent ----
    ush* WT   = (ush*)wsb;
    ush* wqT  = WT;             ush* wkT  = WT + 786432;   ush* wvT  = WT + 1572864;
    ush* wq1T = WT + 2621440;   ush* wk1T = WT + 2883584;  ush* gWT_ = WT + 3145728;
    ush* cWqT = WT + 4194304;   ush* cWkT = WT + 4456448;  ush* cWvT = WT + 4718592;
    ush* cWoT = WT + 5767168;   ush* cWgT = WT + 6815744;  ush* oW1T = WT + 8912896;
    ush* oW2T = WT + 9961472;   ush* oW3T = WT + 12058624;
    (void)wkT; (void)wvT; (void)wk1T; (void)cWvT;
    // ---- activation slabs (byte offsets; lifetimes reused) ----
    ush*  hs_bf   = (ush*)(wsb + 28311552);
    ush*  enc_bf  = (ush*)(wsb + 45088768);
    ush*  qkv_bf  = (ush*)(wsb + 53477376);   // [8192][2560] = q|k|v fused
    ush*  Vt      = (ush*)(wsb + 95420416);   // [8][1024 d][1024 m]
    ush*  h1_bf   = (ush*)(wsb + 112197632);
    ush*  q1k1_bf = (ush*)(wsb + 128974848);  // [8192][512] = q1|k1 fused
    ush*  ctx_bf  = (ush*)(wsb + 137363456);
    float* nump   = (float*)(wsb + 154140672); // 384 floats
    float* denp   = (float*)(wsb + 154142208); // 128 floats
    float* gnn_f  = (float*)(wsb + 154144768);
    float* gnnout_f = (float*)(wsb + 187699200);
    // packed masks:
    //   smb over gnnout_f region: written phase 0, read by attn (phase 2);
    //   gnnout_f first written phase 3.  csmb over hs_bf: written AFTER the
    //   qkv gemm (last hs_bf reader), read by cross (phase 4).
    unsigned int* smb  = (unsigned int*)(wsb + 187699200); // 3,145,728 B
    unsigned int* csmb = (unsigned int*)(wsb + 28311552);  //   524,288 B
    // gc_b: [8192][2048] bf16 concat slab = [gnnout | cctxo]. Written by gnn
    // LN (left, phase 3) and cWo gemm (right, phase 4) -- placed over
    // h1/q1k1/ctx (all dead by then).
    ush*  gc_b      = (ush*)(wsb + 112197632);    // 33,554,432 B
    // reuse (strictly ordered lifetimes):
    ush*  cq_b      = (ush*)(wsb + 53477376);     // over dead qkv (q part)
    ush*  ckv_b     = (ush*)(wsb + 66060288);     // [4096][1280] ck|cv, over qkv
    ush*  cctx_b    = (ush*)(wsb + 95420416);     // over Vt
    ush*  cvt       = (ush*)(wsb + 238030848);    // after gnnout_b region
    float* cctxo_f  = (float*)(wsb + 154144768);  // over gnn_f
    float* gatepre_f= (float*)(wsb + 45088768);   // over enc/cq/ckv (dead after cross)
    ush*  crossout_b= (ush*)(wsb + 221253632);
    float* t_f      = (float*)(wsb + 154144768);  // over cctxo_f
    float* h_f      = (float*)(wsb + 187699200);  // over gnnout_f/smb
    ush*  h_b       = (ush*)(wsb + 28311552);     // over csmb (dead after cross)
    ush*  h2g_b     = (ush*)(wsb + 45088768);     // over gatepre_f (dead after gate_ln)
    float* h3_f     = (float*)(wsb + 154144768);  // over t_f

    const int BIG = 1 << 30;
    dim3 blk(256);
    // ---- phase 0: casts + mask packing + weight transposes ----
    castbf_kernel<<<8192, blk, 0, stream>>>(hs, hs_bf);
    castbf_kernel<<<4096, blk, 0, stream>>>(enc, enc_bf);
    packmask_kernel<<<98304, blk, 0, stream>>>(smask, smb);   // 8*3*1024*1024
    wtrans_kernel<<<dim3(768/32, 1024/32), blk, 0, stream>>>(Wq, wqT, 1024, 768);
    wtrans_kernel<<<dim3(768/32, 1024/32), blk, 0, stream>>>(Wk, wkT, 1024, 768);
    wtrans_kernel<<<dim3(32, 32), blk, 0, stream>>>(Wv, wvT, 1024, 1024);
    wtrans_kernel<<<dim3(8, 32), blk, 0, stream>>>(Wq1, wq1T, 1024, 256);
    wtrans_kernel<<<dim3(8, 32), blk, 0, stream>>>(Wk1, wk1T, 1024, 256);
    wtrans_kernel<<<dim3(32, 32), blk, 0, stream>>>(gW, gWT_, 1024, 1024);
    wtrans_kernel<<<dim3(8, 32), blk, 0, stream>>>(cWq, cWqT, 1024, 256);
    wtrans_kernel<<<dim3(8, 32), blk, 0, stream>>>(cWk, cWkT, 1024, 256);
    wtrans_kernel<<<dim3(32, 32), blk, 0, stream>>>(cWv, cWvT, 1024, 1024);
    wtrans_kernel<<<dim3(32, 32), blk, 0, stream>>>(cWo, cWoT, 1024, 1024);
    wtrans_kernel<<<dim3(32, 64), blk, 0, stream>>>(cWg, cWgT, 2048, 1024);
    wtrans_kernel<<<dim3(32, 32), blk, 0, stream>>>(oW1, oW1T, 1024, 1024);
    wtrans_kernel<<<dim3(64, 32), blk, 0, stream>>>(oW2, oW2T, 1024, 2048);
    wtrans_kernel<<<dim3(32, 64), blk, 0, stream>>>(oW3, oW3T, 2048, 1024);
    // ---- phase 1: fused projections ----
    gemm_bf16_kernel<true,false,false><<<dim3(20, 64), blk, 0, stream>>>(
        hs_bf, 1024, wqT, 1024, bq, bk, bv, 768, 1536, nullptr, qkv_bf, 2560, 2560, 1024);
    packmask_kernel<<<16384, blk, 0, stream>>>(csm, csmb);    // hs_bf now dead
    ln_kernel<<<8192, blk, 0, stream>>>(hs, sent, ent, ln_g, ln_b, nullptr, h1_bf, 1024);
    gemm_bf16_kernel<true,false,false><<<dim3(4, 64), blk, 0, stream>>>(
        h1_bf, 1024, wq1T, 1024, bq1, bk1, nullptr, 256, BIG, nullptr, q1k1_bf, 512, 512, 1024);
    trans_kernel<<<dim3(32, 32, 8), blk, 0, stream>>>(qkv_bf, Vt, 1024, 1024, 2560, 1536);
    // ---- phase 2: attention + loss ----
    attn_mfma_kernel<<<dim3(16, 4, 8), blk, 0, stream>>>(
        qkv_bf, q1k1_bf, Vt, am, smb, ctx_bf, nump, denp);
    loss_reduce_kernel<<<1, blk, 0, stream>>>(nump, denp, out + 8388608);
    // ---- phase 3: gnn (LN writes bf16 into gc_b left half, pitch 2048) ----
    gemm_bf16_kernel<true,false,false><<<dim3(8, 64), blk, 0, stream>>>(
        ctx_bf, 1024, gWT_, 1024, gb, nullptr, nullptr, BIG, BIG, gnn_f, nullptr, 1024, 1024, 1024);
    ln_kernel<<<8192, blk, 0, stream>>>(gnn_f, nullptr, nullptr, gng, gnb,
                                        gnnout_f, gc_b, 2048);
    // ---- phase 4: cross attention + fused gate ----
    gemm_bf16_kernel<true,false,false><<<dim3(2, 64), blk, 0, stream>>>(
        gc_b, 2048, cWqT, 1024, cbq, nullptr, nullptr, BIG, BIG, nullptr, cq_b, 256, 256, 1024);
    gemm_bf16_kernel<true,false,false><<<dim3(10, 32), blk, 0, stream>>>(
        enc_bf, 1024, cWkT, 1024, cbk, cbv, nullptr, 256, BIG, nullptr, ckv_b, 1280, 1280, 1024);
    trans_kernel<<<dim3(16, 32, 8), blk, 0, stream>>>(ckv_b, cvt, 512, 1024, 1280, 256);
    cross_mfma_kernel<<<dim3(16, 4, 8), blk, 0, stream>>>(
        cq_b, ckv_b, cvt, csmb, cctx_b);
    // cWo: fp32 -> cctxo_f (pitch 1024), bf16 -> gc_b right half (pitch 2048)
    gemm_bf16_kernel<true,false,false><<<dim3(8, 64), blk, 0, stream>>>(
        cctx_b, 1024, cWoT, 1024, cbo, nullptr, nullptr, BIG, BIG, cctxo_f, gc_b + 1024, 1024, 2048, 1024);
    // fused gate: [gnnout|cctxo] (K=2048) @ cWg
    gemm_bf16_kernel<true,false,false><<<dim3(8, 64), blk, 0, stream>>>(
        gc_b, 2048, cWgT, 2048, cbg, nullptr, nullptr, BIG, BIG, gatepre_f, nullptr, 1024, 1024, 2048);
    gate_ln_kernel<<<8192, blk, 0, stream>>>(gatepre_f, cctxo_f, gnnout_f,
                                             clg, clb, nullptr, crossout_b);
    // ---- phase 5: output block ----
    gemm_bf16_kernel<true,false,false><<<dim3(8, 64), blk, 0, stream>>>(
        crossout_b, 1024, oW1T, 1024, ob1, nullptr, nullptr, BIG, BIG, t_f, nullptr, 1024, 1024, 1024);
    ln_kernel<<<8192, blk, 0, stream>>>(t_f, hs, nullptr, l1g, l1b, h_f, h_b, 1024);
    gemm_bf16_kernel<true,false,true><<<dim3(16, 64), blk, 0, stream>>>(
        h_b, 1024, oW2T, 1024, ob2, nullptr, nullptr, BIG, BIG, nullptr, h2g_b, 2048, 2048, 1024);
    gemm_bf16_kernel<true,false,false><<<dim3(8, 64), blk, 0, stream>>>(
        h2g_b, 2048, oW3T, 2048, ob3, nullptr, nullptr, BIG, BIG, h3_f, nullptr, 1024, 1024, 2048);
    ln_kernel<<<8192, blk, 0, stream>>>(h3_f, h_f, nullptr, l3g, l3b, out, nullptr, 1024);
}

// Round 6
// 1157.038 us; speedup vs baseline: 1.1033x; 1.1033x over previous
//
#include <hip/hip_runtime.h>
#include <math.h>

#define DEV __device__ __forceinline__

typedef short short8 __attribute__((ext_vector_type(8)));
typedef float float4v __attribute__((ext_vector_type(4)));

// round-to-nearest-even fp32 -> bf16 (values here are finite; no NaN path)
DEV unsigned short f2bf(float f) {
    union { float f; unsigned u; } v; v.f = f;
    unsigned r = v.u + 0x7FFFu + ((v.u >> 16) & 1u);
    return (unsigned short)(r >> 16);
}

// async global->LDS, 16B per lane; LDS dest must be wave-uniform base (+lane*16)
DEV void async16(const unsigned short* g, unsigned short* l) {
    __builtin_amdgcn_global_load_lds(
        (const __attribute__((address_space(1))) unsigned int*)g,
        (__attribute__((address_space(3))) unsigned int*)l, 16, 0, 0);
}

// block-wide reduction (256 threads). mode 0 = sum, 1 = max.
DEV float block_reduce(float v, int mode) {
    #pragma unroll
    for (int off = 32; off; off >>= 1) {
        float o = __shfl_xor(v, off);
        v = mode ? fmaxf(v, o) : (v + o);
    }
    __shared__ float sbuf[4];
    __syncthreads();
    if ((threadIdx.x & 63) == 0) sbuf[threadIdx.x >> 6] = v;
    __syncthreads();
    float r = sbuf[0];
    #pragma unroll
    for (int w = 1; w < 4; w++) r = mode ? fmaxf(r, sbuf[w]) : (r + sbuf[w]);
    return r;
}

// ---------------------------------------------------------------------------
// bf16 MFMA GEMM: C[M,N] = A[M,K] @ Wt[N,K]^T (+bias)(+=Cf)(GELU)
// m97 structure: 128x128 tile, BK=32, linear LDS [row][32], staging via
// global_load_lds width=16 (4 issues/wave/K-step), 2 barriers per K-step.
// 3-way split bias (fused N-concat projections). Cb has its own pitch Nb
// (lets bf16 output land inside a wider concat slab).
// ---------------------------------------------------------------------------
template <bool BIAS, bool ACCUM, bool GELU>
__global__ __launch_bounds__(256) void gemm_bf16_kernel(
    const unsigned short* __restrict__ A, int lda,
    const unsigned short* __restrict__ Bt, int ldb,
    const float* __restrict__ bias, const float* __restrict__ bias2,
    const float* __restrict__ bias3, int ns1, int ns2,
    float* __restrict__ Cf, unsigned short* __restrict__ Cb,
    int N, int Nb, int K)
{
    __shared__ unsigned short As[128 * 32];   // linear: row*32 + k  (no pad)
    __shared__ unsigned short Bs[128 * 32];
    const int tid = threadIdx.x;
    const int w = tid >> 6, lane = tid & 63;
    const int l15 = lane & 15, quad = lane >> 4;
    const int m0 = blockIdx.y * 128, n0 = blockIdx.x * 128;
    const int wm = (w >> 1) * 64, wn = (w & 1) * 64;
    const int lr = lane >> 2, lc = (lane & 3) * 8;  // lane -> (row-in-16, k-chunk)

    float4v acc[4][4];
    #pragma unroll
    for (int i = 0; i < 4; i++)
        #pragma unroll
        for (int j = 0; j < 4; j++) acc[i][j] = (float4v){0.f, 0.f, 0.f, 0.f};

    const unsigned short* Ab = A  + (size_t)(m0 + w * 16 + lr) * lda + lc;
    const unsigned short* Bb = Bt + (size_t)(n0 + w * 16 + lr) * ldb + lc;
    unsigned short* AsW = As + (w * 16) * 32;
    unsigned short* BsW = Bs + (w * 16) * 32;

    for (int k0 = 0; k0 < K; k0 += 32) {
        __syncthreads();                       // prior reads done before overwrite
        async16(Ab + k0, AsW);
        async16(Ab + (size_t)64 * lda + k0, AsW + 64 * 32);
        async16(Bb + k0, BsW);
        async16(Bb + (size_t)64 * ldb + k0, BsW + 64 * 32);
        __syncthreads();                       // compiler drains vmcnt here
        short8 Af[4], Bf[4];
        #pragma unroll
        for (int mt = 0; mt < 4; mt++)
            Af[mt] = *(const short8*)(As + (wm + mt * 16 + l15) * 32 + quad * 8);
        #pragma unroll
        for (int nt = 0; nt < 4; nt++)
            Bf[nt] = *(const short8*)(Bs + (wn + nt * 16 + l15) * 32 + quad * 8);
        #pragma unroll
        for (int mt = 0; mt < 4; mt++)
            #pragma unroll
            for (int nt = 0; nt < 4; nt++)
                acc[mt][nt] = __builtin_amdgcn_mfma_f32_16x16x32_bf16(
                    Af[mt], Bf[nt], acc[mt][nt], 0, 0, 0);
    }

    #pragma unroll
    for (int nt = 0; nt < 4; nt++) {
        const int n = n0 + wn + nt * 16 + l15;
        float bv = 0.f;
        if (BIAS) bv = (n < ns1) ? bias[n] : (n < ns2) ? bias2[n - ns1]
                                                       : bias3[n - ns2];
        #pragma unroll
        for (int mt = 0; mt < 4; mt++) {
            #pragma unroll
            for (int r = 0; r < 4; r++) {
                const int m = m0 + wm + mt * 16 + quad * 4 + r;
                const size_t off = (size_t)m * N + n;
                float v = acc[mt][nt][r] + bv;
                if (ACCUM) v += Cf[off];
                if (GELU) v = 0.5f * v * (1.f + erff(v * 0.70710678118654752f));
                if (Cf) Cf[off] = v;
                if (Cb) Cb[(size_t)m * Nb + n] = f2bf(v);
            }
        }
    }
}

// ---------------------------------------------------------------------------
// Weight transpose+cast: W fp32 [K][N] -> Wt bf16 [N][K]
// ---------------------------------------------------------------------------
__global__ __launch_bounds__(256) void wtrans_kernel(
    const float* __restrict__ W, unsigned short* __restrict__ Wt, int K, int N)
{
    __shared__ float t[32][33];
    const int n0 = blockIdx.x * 32, k0 = blockIdx.y * 32;
    const int c = threadIdx.x & 31, r8 = threadIdx.x >> 5;
    #pragma unroll
    for (int i = 0; i < 4; i++) {
        const int r = r8 + i * 8;
        t[r][c] = W[(size_t)(k0 + r) * N + n0 + c];
    }
    __syncthreads();
    #pragma unroll
    for (int i = 0; i < 4; i++) {
        const int r = r8 + i * 8;
        Wt[(size_t)(n0 + r) * K + k0 + c] = f2bf(t[c][r]);
    }
}

// bf16 transpose per batch: in [b][R][vpitch] cols [voff,voff+C) -> out [b][C][R]
__global__ __launch_bounds__(256) void trans_kernel(
    const unsigned short* __restrict__ v, unsigned short* __restrict__ Vt,
    int R, int C, int vpitch, int voff)
{
    __shared__ unsigned short t[32][33];
    const int b = blockIdx.z, r0 = blockIdx.x * 32, c0 = blockIdx.y * 32;
    const int c = threadIdx.x & 31, r8 = threadIdx.x >> 5;
    #pragma unroll
    for (int i = 0; i < 4; i++) {
        const int r = r8 + i * 8;
        t[r][c] = v[((size_t)b * R + r0 + r) * vpitch + voff + c0 + c];
    }
    __syncthreads();
    #pragma unroll
    for (int i = 0; i < 4; i++) {
        const int r = r8 + i * 8;
        Vt[((size_t)b * C + c0 + r) * R + r0 + c] = t[c][r];
    }
}

// fp32 -> bf16 elementwise (count = grid*256*4)
__global__ __launch_bounds__(256) void castbf_kernel(
    const float* __restrict__ x, unsigned short* __restrict__ y)
{
    const size_t i = ((size_t)blockIdx.x * 256 + threadIdx.x) * 4;
    float4 v = *(const float4*)(x + i);
    ushort4 o;
    o.x = f2bf(v.x); o.y = f2bf(v.y); o.z = f2bf(v.z); o.w = f2bf(v.w);
    *(ushort4*)(y + i) = o;
}

// pack a 0/1 fp32 mask into bits: bit i of word w = (x[32w+i] > 0.5)
__global__ __launch_bounds__(256) void packmask_kernel(
    const float* __restrict__ x, unsigned int* __restrict__ bits)
{
    const size_t idx = (size_t)blockIdx.x * 256 + threadIdx.x;
    const unsigned long long m = __ballot(x[idx] > 0.5f);
    const int lane = threadIdx.x & 63;
    if (lane == 0)  bits[idx >> 5] = (unsigned)m;
    if (lane == 32) bits[idx >> 5] = (unsigned)(m >> 32);
}

// ---------------------------------------------------------------------------
// LayerNorm over 1024 cols; optional residuals; fp32 and/or bf16 outputs.
// outb has its own row pitch (base_b) so bf16 can land in a concat slab.
// ---------------------------------------------------------------------------
DEV void ln_finish(float4 xv, const float* __restrict__ g,
                   const float* __restrict__ bb, float* __restrict__ outf,
                   unsigned short* __restrict__ outb, size_t base_f, size_t base_b)
{
    float s  = xv.x + xv.y + xv.z + xv.w;
    float s2 = xv.x * xv.x + xv.y * xv.y + xv.z * xv.z + xv.w * xv.w;
    #pragma unroll
    for (int off = 32; off; off >>= 1) {
        s += __shfl_xor(s, off);
        s2 += __shfl_xor(s2, off);
    }
    __shared__ float sa[4], sb[4];
    if ((threadIdx.x & 63) == 0) {
        sa[threadIdx.x >> 6] = s; sb[threadIdx.x >> 6] = s2;
    }
    __syncthreads();
    s  = sa[0] + sa[1] + sa[2] + sa[3];
    s2 = sb[0] + sb[1] + sb[2] + sb[3];
    const float mu  = s * (1.f / 1024.f);
    const float var = fmaxf(s2 * (1.f / 1024.f) - mu * mu, 0.f);
    const float inv = rsqrtf(var + 1e-12f);
    const int tid = threadIdx.x;
    float4 gv = ((const float4*)g)[tid];
    float4 bv = ((const float4*)bb)[tid];
    float4 o;
    o.x = (xv.x - mu) * inv * gv.x + bv.x;
    o.y = (xv.y - mu) * inv * gv.y + bv.y;
    o.z = (xv.z - mu) * inv * gv.z + bv.z;
    o.w = (xv.w - mu) * inv * gv.w + bv.w;
    if (outf) ((float4*)(outf + base_f))[tid] = o;
    if (outb) {
        ushort4 ob;
        ob.x = f2bf(o.x); ob.y = f2bf(o.y); ob.z = f2bf(o.z); ob.w = f2bf(o.w);
        ((ushort4*)(outb + base_b))[tid] = ob;
    }
}

__global__ __launch_bounds__(256) void ln_kernel(
    const float* __restrict__ x, const float* __restrict__ r1,
    const float* __restrict__ r2, const float* __restrict__ g,
    const float* __restrict__ bb, float* __restrict__ outf,
    unsigned short* __restrict__ outb, int obp)
{
    const size_t base = (size_t)blockIdx.x * 1024;
    const size_t base_b = (size_t)blockIdx.x * obp;
    const int tid = threadIdx.x;
    float4 xv = ((const float4*)(x + base))[tid];
    if (r1) {
        float4 a = ((const float4*)(r1 + base))[tid];
        xv.x += a.x; xv.y += a.y; xv.z += a.z; xv.w += a.w;
    }
    if (r2) {
        float4 a = ((const float4*)(r2 + base))[tid];
        xv.x += a.x; xv.y += a.y; xv.z += a.z; xv.w += a.w;
    }
    ln_finish(xv, g, bb, outf, outb, base, base_b);
}

__global__ __launch_bounds__(256) void gate_ln_kernel(
    const float* __restrict__ gpre, const float* __restrict__ co,
    const float* __restrict__ gn, const float* __restrict__ g,
    const float* __restrict__ bb, float* __restrict__ outf,
    unsigned short* __restrict__ outb)
{
    const size_t base = (size_t)blockIdx.x * 1024;
    const int tid = threadIdx.x;
    float4 gp = ((const float4*)(gpre + base))[tid];
    float4 cv = ((const float4*)(co + base))[tid];
    float4 gv = ((const float4*)(gn + base))[tid];
    float4 xv; float s;
    s = 1.f / (1.f + __expf(-gp.x)); xv.x = s * cv.x + (1.f - s) * gv.x;
    s = 1.f / (1.f + __expf(-gp.y)); xv.y = s * cv.y + (1.f - s) * gv.y;
    s = 1.f / (1.f + __expf(-gp.z)); xv.z = s * cv.z + (1.f - s) * gv.z;
    s = 1.f / (1.f + __expf(-gp.w)); xv.w = s * cv.w + (1.f - s) * gv.w;
    ln_finish(xv, g, bb, outf, outb, base, base);
}

// ---------------------------------------------------------------------------
// MFMA flash attention + inline focal loss, v7: round-4 structure + async
// double-buffer via global_load_lds (T3-minimum 2-phase): STAGE(buf^1) is
// issued before computing buf, ONE barrier per iteration drains vmcnt after
// the loads had the whole compute phase to fly. No registers held across
// compute (round-5 spill fix). K LDS = 2-row 1024B chunks @1056B stride
// (wave-linear writes for global_load_lds; pad between chunks keeps the
// bank spread of the old pitch-264 layout). V LDS = tight [d][32].
// XCD swizzle keeps each (b,h)'s K/V in one XCD's L2.
// ---------------------------------------------------------------------------
__global__ __launch_bounds__(256) void attn_mfma_kernel(
    const unsigned short* __restrict__ qkv,  // [B*N,2560] bf16
    const unsigned short* __restrict__ q1k1, // [B*N,512]  bf16
    const unsigned short* __restrict__ Vt,   // [B*1024(d)][1024(m)] bf16
    const float* __restrict__ am,            // [B*N]
    const unsigned int* __restrict__ smb,    // packed smask bits [B,3,N,N/32]
    unsigned short* __restrict__ ctx,        // [B*N,1024] bf16
    float* __restrict__ nump, float* __restrict__ denp)
{
    // XCD swizzle: 512 blocks, 8 XCDs; each XCD owns 4 complete (b,h) groups.
    const int bid0 = blockIdx.x + 16 * blockIdx.y + 64 * blockIdx.z;
    const int xcd = bid0 & 7, s = bid0 >> 3;
    const int grp = xcd + 8 * (s >> 4);      // 0..31 = b*4 + h
    const int nb = s & 15;
    const int h = grp & 3, b = grp >> 2;
    const int tid = threadIdx.x;
    const int w = tid >> 6, lane = tid & 63;
    const int l15 = lane & 15, quad = lane >> 4;
    const int n0 = nb * 64;

    __shared__ unsigned short Ks[2][16 * 528];  // 16 chunks (2 rows) @ 1056B
    __shared__ unsigned short Vs[2][256 * 32];  // tight [d][m]
    __shared__ unsigned short Ps[4][16 * 40];   // per-wave P tile

    const unsigned short* qsrc; const unsigned short* ksrc; int pitch;
    if (h == 0) { qsrc = q1k1;                ksrc = q1k1 + 256;                pitch = 512; }
    else        { qsrc = qkv + (h - 1) * 256; ksrc = qkv + 768 + (h - 1) * 256; pitch = 2560; }

    // Q fragments directly from global (resident across the loop)
    short8 Qf[8];
    {
        const unsigned short* qrow =
            qsrc + (size_t)(b * 1024 + n0 + w * 16 + l15) * pitch;
        #pragma unroll
        for (int kk = 0; kk < 8; kk++)
            Qf[kk] = *(const short8*)(qrow + kk * 32 + quad * 8);
    }

    // per-lane staging sources: wave w stages chunks c=4w..4w+3 of K and V.
    // K chunk c: rows 2c+(lane>>5), col (lane&31)*8 -> LDS c*528 (+lane*8 HW)
    // V chunk c: d 16c+(lane>>2), m (lane&3)*8 -> LDS c*512
    const int vrow0 = b * 1024 + h * 256;
    const unsigned short* kp[4]; const unsigned short* vp[4];
    #pragma unroll
    for (int j = 0; j < 4; j++) {
        const int c = w * 4 + j;
        kp[j] = ksrc + (size_t)(b * 1024 + 2 * c + (lane >> 5)) * pitch + (lane & 31) * 8;
        vp[j] = Vt + (size_t)(vrow0 + 16 * c + (lane >> 2)) * 1024 + (lane & 3) * 8;
    }

    float4v O[16];
    #pragma unroll
    for (int i = 0; i < 16; i++) O[i] = (float4v){0.f, 0.f, 0.f, 0.f};
    float lsum[4] = {0.f, 0.f, 0.f, 0.f};
    float flsum = 0.f, dencnt = 0.f;
    const int nrow_base = n0 + w * 16 + quad * 4;  // + r = this lane's rows
    const float* amrow = am + b * 1024;
    float amn[4];
    #pragma unroll
    for (int r = 0; r < 4; r++) amn[r] = amrow[nrow_base + r];
    const unsigned int* smw = (h > 0)
        ? smb + ((size_t)(b * 3 + (h - 1)) << 15) : nullptr;   // 1024*32 words

    // prologue: stage tile 0 into buffer 0
    #pragma unroll
    for (int j = 0; j < 4; j++) {
        const int c = w * 4 + j;
        async16(kp[j], &Ks[0][c * 528]);
        async16(vp[j], &Vs[0][c * 512]);
        kp[j] += (size_t)32 * pitch; vp[j] += 32;
    }
    __syncthreads();
    int cur = 0;

    for (int m0 = 0; m0 < 1024; m0 += 32) {
        const bool more = (m0 + 32 < 1024);
        if (more) {                              // stage next tile (async, LDS)
            #pragma unroll
            for (int j = 0; j < 4; j++) {
                const int c = w * 4 + j;
                async16(kp[j], &Ks[cur ^ 1][c * 528]);
                async16(vp[j], &Vs[cur ^ 1][c * 512]);
                kp[j] += (size_t)32 * pitch; vp[j] += 32;
            }
        }
        const unsigned short* Ksc = &Ks[cur][0];
        const unsigned short* Vsc = &Vs[cur][0];

        // S = Q K^T (16 x 32 per wave); K row r at chunk (r>>1), half (r&1)
        float4v S[2];
        #pragma unroll
        for (int st = 0; st < 2; st++) {
            float4v a = (float4v){0.f, 0.f, 0.f, 0.f};
            const int r = st * 16 + l15;
            const unsigned short* krow = Ksc + (r >> 1) * 528 + (r & 1) * 256;
            #pragma unroll
            for (int kk = 0; kk < 8; kk++) {
                short8 Kf = *(const short8*)(krow + kk * 32 + quad * 8);
                a = __builtin_amdgcn_mfma_f32_16x16x32_bf16(Qf[kk], Kf, a, 0, 0, 0);
            }
            S[st] = a;
        }

        // packed structure-mask words: one per q-row, covers cols [m0,m0+32)
        unsigned int wb[4];
        if (h > 0) {
            #pragma unroll
            for (int r = 0; r < 4; r++)
                wb[r] = smw[(size_t)(nrow_base + r) * 32 + (m0 >> 5)];
        }

        // masks, focal loss, exp (fixed-max softmax)
        float e[2][4];
        #pragma unroll
        for (int st = 0; st < 2; st++) {
            const int mcol = m0 + st * 16 + l15;
            const float amm = amrow[mcol];
            const float am0 = (1.f - amm) * (-10000.f);
            #pragma unroll
            for (int r = 0; r < 4; r++) {
                const float sraw = S[st][r];
                float scv;
                if (h > 0) {
                    const float t = (float)((wb[r] >> (st * 16 + l15)) & 1u);
                    const int nrow = nrow_base + r;
                    const float s3 = sraw + am0;
                    const float idxw =
                        ((amn[r] * amm * ((mcol == nrow) ? 0.f : 1.f)) > 0.5f) ? 1.f : 0.f;
                    // shared-transcendental focal loss:
                    // E=exp(-|s3|); softplus(s3)=max(s3,0)+log(1+E);
                    // p=sigmoid(s3)=(s3>=0 ? 1 : E)/(1+E);
                    // -log_sigmoid(s3)=softplus(-s3)=softplus(s3)-s3
                    const float E = __expf(-fabsf(s3));
                    const float L = __logf(1.f + E);
                    const float R = 1.f / (1.f + E);
                    const float p = (s3 >= 0.f) ? R : E * R;
                    const float sp = fmaxf(s3, 0.f) + L;      // softplus(s3)
                    const float omp = 1.f - p;
                    flsum += idxw * (0.25f * t * omp * omp * (sp - s3)
                                   + 0.75f * (1.f - t) * p * p * sp);
                    dencnt += idxw;
                    scv = sraw * 0.0625f + (1.f - t) * (-10000.f);
                } else {
                    scv = sraw * 0.0625f + am0;
                }
                const float ev = __expf(fminf(scv, 30.f));  // overflow guard
                e[st][r] = ev;
                lsum[r] += ev;
            }
        }

        // P: C-layout -> LDS -> A-layout (per-wave buffer; no barrier needed)
        #pragma unroll
        for (int st = 0; st < 2; st++)
            #pragma unroll
            for (int r = 0; r < 4; r++)
                Ps[w][(quad * 4 + r) * 40 + st * 16 + l15] = f2bf(e[st][r]);
        const short8 Pf = *(const short8*)(&Ps[w][l15 * 40 + quad * 8]);
        #pragma unroll
        for (int dt = 0; dt < 16; dt++) {
            short8 Vf = *(const short8*)(Vsc + (dt * 16 + l15) * 32 + quad * 8);
            O[dt] = __builtin_amdgcn_mfma_f32_16x16x32_bf16(Pf, Vf, O[dt], 0, 0, 0);
        }

        if (more) {                              // drains vmcnt: next tile ready
            __syncthreads();
            cur ^= 1;
        }
    }

    // one row-sum reduction across the 16 col-lanes, then write out
    float rinv[4];
    #pragma unroll
    for (int r = 0; r < 4; r++) {
        float s2 = lsum[r];
        #pragma unroll
        for (int off = 8; off; off >>= 1) s2 += __shfl_xor(s2, off);
        rinv[r] = 1.f / s2;
    }
    #pragma unroll
    for (int dt = 0; dt < 16; dt++)
        #pragma unroll
        for (int r = 0; r < 4; r++)
            ctx[(size_t)(b * 1024 + nrow_base + r) * 1024 + h * 256 + dt * 16 + l15]
                = f2bf(O[dt][r] * rinv[r]);

    if (h > 0) {
        const float fb = block_reduce(flsum, 0);
        if (tid == 0) nump[(b * 3 + (h - 1)) * 16 + nb] = fb;
        if (h == 1) {
            const float db = block_reduce(dencnt, 0);
            if (tid == 0) denp[b * 16 + nb] = db;
        }
    }
}

// ---------------------------------------------------------------------------
// MFMA cross attention v7: async double-buffer via global_load_lds, one
// barrier per iteration. K LDS = 8-row 1024B chunks @1056B stride; V tight.
// qk-dim 64, v-dim 256, M=512 keys. K from fused cK|cV output (pitch 1280).
// ---------------------------------------------------------------------------
__global__ __launch_bounds__(256) void cross_mfma_kernel(
    const unsigned short* __restrict__ cq,   // [B*N, 256] bf16 (4 heads x 64)
    const unsigned short* __restrict__ ckv,  // [B*512, 1280] bf16
    const unsigned short* __restrict__ cvt,  // [B][1024(d)][512(m)] bf16
    const unsigned int* __restrict__ csmb,   // packed bits [B,N,512/32]
    unsigned short* __restrict__ cctx)       // [B*N, 1024] bf16
{
    const int bid0 = blockIdx.x + 16 * blockIdx.y + 64 * blockIdx.z;
    const int xcd = bid0 & 7, s = bid0 >> 3;
    const int grp = xcd + 8 * (s >> 4);
    const int nb = s & 15;
    const int h = grp & 3, b = grp >> 2;
    const int tid = threadIdx.x;
    const int w = tid >> 6, lane = tid & 63;
    const int l15 = lane & 15, quad = lane >> 4;
    const int n0 = nb * 64;

    __shared__ unsigned short Ks[2][4 * 528];   // 4 chunks (8 rows) @ 1056B
    __shared__ unsigned short Vs[2][256 * 32];  // tight [d][m]
    __shared__ unsigned short Ps[4][16 * 40];

    short8 Qf[2];
    {
        const unsigned short* qrow =
            cq + (size_t)(b * 1024 + n0 + w * 16 + l15) * 256 + h * 64;
        #pragma unroll
        for (int kk = 0; kk < 2; kk++)
            Qf[kk] = *(const short8*)(qrow + kk * 32 + quad * 8);
    }

    // staging: wave w stages K chunk w (rows 8w+(lane>>3), col (lane&7)*8)
    // and V chunks c=4w..4w+3 (d 16c+(lane>>2), m (lane&3)*8)
    const int vrow0 = b * 1024 + h * 256;
    const unsigned short* kp =
        ckv + (size_t)(b * 512 + 8 * w + (lane >> 3)) * 1280 + h * 64 + (lane & 7) * 8;
    const unsigned short* vp[4];
    #pragma unroll
    for (int j = 0; j < 4; j++) {
        const int c = w * 4 + j;
        vp[j] = cvt + (size_t)(vrow0 + 16 * c + (lane >> 2)) * 512 + (lane & 3) * 8;
    }

    float4v O[16];
    #pragma unroll
    for (int i = 0; i < 16; i++) O[i] = (float4v){0.f, 0.f, 0.f, 0.f};
    float lsum[4] = {0.f, 0.f, 0.f, 0.f};
    const int nrow_base = n0 + w * 16 + quad * 4;
    const unsigned int* csw = csmb + (size_t)(b * 1024) * 16;  // 16 words/row

    // prologue: stage tile 0 into buffer 0
    async16(kp, &Ks[0][w * 528]);
    kp += (size_t)32 * 1280;
    #pragma unroll
    for (int j = 0; j < 4; j++) {
        async16(vp[j], &Vs[0][(w * 4 + j) * 512]);
        vp[j] += 32;
    }
    __syncthreads();
    int cur = 0;

    for (int m0 = 0; m0 < 512; m0 += 32) {
        const bool more = (m0 + 32 < 512);
        if (more) {
            async16(kp, &Ks[cur ^ 1][w * 528]);
            kp += (size_t)32 * 1280;
            #pragma unroll
            for (int j = 0; j < 4; j++) {
                async16(vp[j], &Vs[cur ^ 1][(w * 4 + j) * 512]);
                vp[j] += 32;
            }
        }
        const unsigned short* Ksc = &Ks[cur][0];
        const unsigned short* Vsc = &Vs[cur][0];

        float4v S[2];
        #pragma unroll
        for (int st = 0; st < 2; st++) {
            float4v a = (float4v){0.f, 0.f, 0.f, 0.f};
            const int r = st * 16 + l15;
            const unsigned short* krow = Ksc + (r >> 3) * 528 + (r & 7) * 64;
            #pragma unroll
            for (int kk = 0; kk < 2; kk++) {
                short8 Kf = *(const short8*)(krow + kk * 32 + quad * 8);
                a = __builtin_amdgcn_mfma_f32_16x16x32_bf16(Qf[kk], Kf, a, 0, 0, 0);
            }
            S[st] = a;
        }

        unsigned int wb[4];
        #pragma unroll
        for (int r = 0; r < 4; r++)
            wb[r] = csw[(size_t)(nrow_base + r) * 16 + (m0 >> 5)];

        float e[2][4];
        #pragma unroll
        for (int st = 0; st < 2; st++) {
            #pragma unroll
            for (int r = 0; r < 4; r++) {
                const float msk = (float)((wb[r] >> (st * 16 + l15)) & 1u);
                const float scv = S[st][r] * 0.125f + (1.f - msk) * (-10000.f);
                const float ev = __expf(fminf(scv, 30.f));
                e[st][r] = ev;
                lsum[r] += ev;
            }
        }

        #pragma unroll
        for (int st = 0; st < 2; st++)
            #pragma unroll
            for (int r = 0; r < 4; r++)
                Ps[w][(quad * 4 + r) * 40 + st * 16 + l15] = f2bf(e[st][r]);
        const short8 Pf = *(const short8*)(&Ps[w][l15 * 40 + quad * 8]);
        #pragma unroll
        for (int dt = 0; dt < 16; dt++) {
            short8 Vf = *(const short8*)(Vsc + (dt * 16 + l15) * 32 + quad * 8);
            O[dt] = __builtin_amdgcn_mfma_f32_16x16x32_bf16(Pf, Vf, O[dt], 0, 0, 0);
        }

        if (more) {
            __syncthreads();
            cur ^= 1;
        }
    }

    float rinv[4];
    #pragma unroll
    for (int r = 0; r < 4; r++) {
        float s2 = lsum[r];
        #pragma unroll
        for (int off = 8; off; off >>= 1) s2 += __shfl_xor(s2, off);
        rinv[r] = 1.f / s2;
    }
    #pragma unroll
    for (int dt = 0; dt < 16; dt++)
        #pragma unroll
        for (int r = 0; r < 4; r++)
            cctx[(size_t)(b * 1024 + nrow_base + r) * 1024 + h * 256 + dt * 16 + l15]
                = f2bf(O[dt][r] * rinv[r]);
}

// loss = sum(nump[384]) / (3 * sum(denp[128])), deterministic
__global__ __launch_bounds__(256) void loss_reduce_kernel(
    const float* __restrict__ nump, const float* __restrict__ denp,
    float* __restrict__ out)
{
    __shared__ double sn[256], sd[256];
    const int tid = threadIdx.x;
    double ns = 0.0, ds = 0.0;
    for (int i = tid; i < 384; i += 256) ns += (double)nump[i];
    for (int i = tid; i < 128; i += 256) ds += (double)denp[i];
    sn[tid] = ns; sd[tid] = ds;
    __syncthreads();
    for (int off = 128; off; off >>= 1) {
        if (tid < off) { sn[tid] += sn[tid + off]; sd[tid] += sd[tid + off]; }
        __syncthreads();
    }
    if (tid == 0) out[0] = (float)(sn[0] / (3.0 * sd[0]));
}

// ---------------------------------------------------------------------------
extern "C" void kernel_launch(void* const* d_in, const int* in_sizes, int n_in,
                              void* d_out, int out_size, void* d_ws, size_t ws_size,
                              hipStream_t stream)
{
    (void)in_sizes; (void)n_in; (void)out_size; (void)ws_size;
    const float* hs   = (const float*)d_in[0];
    const float* am   = (const float*)d_in[1];
    const float* smask= (const float*)d_in[2];
    const float* sent = (const float*)d_in[3];
    const float* ent  = (const float*)d_in[4];
    const float* csm  = (const float*)d_in[5];
    const float* enc  = (const float*)d_in[6];
    const float* Wq  = (const float*)d_in[8];  const float* bq  = (const float*)d_in[9];
    const float* Wk  = (const float*)d_in[10]; const float* bk  = (const float*)d_in[11];
    const float* Wv  = (const float*)d_in[12]; const float* bv  = (const float*)d_in[13];
    const float* Wq1 = (const float*)d_in[14]; const float* bq1 = (const float*)d_in[15];
    const float* Wk1 = (const float*)d_in[16]; const float* bk1 = (const float*)d_in[17];
    const float* ln_g= (const float*)d_in[18]; const float* ln_b= (const float*)d_in[19];
    const float* gW  = (const float*)d_in[20]; const float* gb  = (const float*)d_in[21];
    const float* gng = (const float*)d_in[22]; const float* gnb = (const float*)d_in[23];
    const float* cWq = (const float*)d_in[24]; const float* cbq = (const float*)d_in[25];
    const float* cWk = (const float*)d_in[26]; const float* cbk = (const float*)d_in[27];
    const float* cWv = (const float*)d_in[28]; const float* cbv = (const float*)d_in[29];
    const float* cWo = (const float*)d_in[30]; const float* cbo = (const float*)d_in[31];
    const float* cWg = (const float*)d_in[32]; const float* cbg = (const float*)d_in[33];
    const float* clg = (const float*)d_in[34]; const float* clb = (const float*)d_in[35];
    const float* oW1 = (const float*)d_in[36]; const float* ob1 = (const float*)d_in[37];
    const float* l1g = (const float*)d_in[38]; const float* l1b = (const float*)d_in[39];
    const float* oW2 = (const float*)d_in[40]; const float* ob2 = (const float*)d_in[41];
    const float* oW3 = (const float*)d_in[42]; const float* ob3 = (const float*)d_in[43];
    const float* l3g = (const float*)d_in[44]; const float* l3b = (const float*)d_in[45];
    float* out = (float*)d_out;

    typedef unsigned short ush;
    char* wsb = (char*)d_ws;
    // ---- weight-transpose arena (bf16); wq|wk|wv, wq1|wk1, cWk|cWv adjacent ----
    ush* WT   = (ush*)wsb;
    ush* wqT  = WT;             ush* wkT  = WT + 786432;   ush* wvT  = WT + 1572864;
    ush* wq1T = WT + 2621440;   ush* wk1T = WT + 2883584;  ush* gWT_ = WT + 3145728;
    ush* cWqT = WT + 4194304;   ush* cWkT = WT + 4456448;  ush* cWvT = WT + 4718592;
    ush* cWoT = WT + 5767168;   ush* cWgT = WT + 6815744;  ush* oW1T = WT + 8912896;
    ush* oW2T = WT + 9961472;   ush* oW3T = WT + 12058624;
    (void)wkT; (void)wvT; (void)wk1T; (void)cWvT;
    // ---- activation slabs (byte offsets; lifetimes reused) ----
    ush*  hs_bf   = (ush*)(wsb + 28311552);
    ush*  enc_bf  = (ush*)(wsb + 45088768);
    ush*  qkv_bf  = (ush*)(wsb + 53477376);   // [8192][2560] = q|k|v fused
    ush*  Vt      = (ush*)(wsb + 95420416);   // [8][1024 d][1024 m]
    ush*  h1_bf   = (ush*)(wsb + 112197632);
    ush*  q1k1_bf = (ush*)(wsb + 128974848);  // [8192][512] = q1|k1 fused
    ush*  ctx_bf  = (ush*)(wsb + 137363456);
    float* nump   = (float*)(wsb + 154140672); // 384 floats
    float* denp   = (float*)(wsb + 154142208); // 128 floats
    float* gnn_f  = (float*)(wsb + 154144768);
    float* gnnout_f = (float*)(wsb + 187699200);
    // packed masks:
    //   smb over gnnout_f region: written phase 0, read by attn (phase 2);
    //   gnnout_f first written phase 3.  csmb over hs_bf: written AFTER the
    //   qkv gemm (last hs_bf reader), read by cross (phase 4).
    unsigned int* smb  = (unsigned int*)(wsb + 187699200); // 3,145,728 B
    unsigned int* csmb = (unsigned int*)(wsb + 28311552);  //   524,288 B
    // gc_b: [8192][2048] bf16 concat slab = [gnnout | cctxo]. Written by gnn
    // LN (left, phase 3) and cWo gemm (right, phase 4) -- placed over
    // h1/q1k1/ctx (all dead by then).
    ush*  gc_b      = (ush*)(wsb + 112197632);    // 33,554,432 B
    // reuse (strictly ordered lifetimes):
    ush*  cq_b      = (ush*)(wsb + 53477376);     // over dead qkv (q part)
    ush*  ckv_b     = (ush*)(wsb + 66060288);     // [4096][1280] ck|cv, over qkv
    ush*  cctx_b    = (ush*)(wsb + 95420416);     // over Vt
    ush*  cvt       = (ush*)(wsb + 238030848);    // after gnnout_b region
    float* cctxo_f  = (float*)(wsb + 154144768);  // over gnn_f
    float* gatepre_f= (float*)(wsb + 45088768);   // over enc/cq/ckv (dead after cross)
    ush*  crossout_b= (ush*)(wsb + 221253632);
    float* t_f      = (float*)(wsb + 154144768);  // over cctxo_f
    float* h_f      = (float*)(wsb + 187699200);  // over gnnout_f/smb
    ush*  h_b       = (ush*)(wsb + 28311552);     // over csmb (dead after cross)
    ush*  h2g_b     = (ush*)(wsb + 45088768);     // over gatepre_f (dead after gate_ln)
    float* h3_f     = (float*)(wsb + 154144768);  // over t_f

    const int BIG = 1 << 30;
    dim3 blk(256);
    // ---- phase 0: casts + mask packing + weight transposes ----
    castbf_kernel<<<8192, blk, 0, stream>>>(hs, hs_bf);
    castbf_kernel<<<4096, blk, 0, stream>>>(enc, enc_bf);
    packmask_kernel<<<98304, blk, 0, stream>>>(smask, smb);   // 8*3*1024*1024
    wtrans_kernel<<<dim3(768/32, 1024/32), blk, 0, stream>>>(Wq, wqT, 1024, 768);
    wtrans_kernel<<<dim3(768/32, 1024/32), blk, 0, stream>>>(Wk, wkT, 1024, 768);
    wtrans_kernel<<<dim3(32, 32), blk, 0, stream>>>(Wv, wvT, 1024, 1024);
    wtrans_kernel<<<dim3(8, 32), blk, 0, stream>>>(Wq1, wq1T, 1024, 256);
    wtrans_kernel<<<dim3(8, 32), blk, 0, stream>>>(Wk1, wk1T, 1024, 256);
    wtrans_kernel<<<dim3(32, 32), blk, 0, stream>>>(gW, gWT_, 1024, 1024);
    wtrans_kernel<<<dim3(8, 32), blk, 0, stream>>>(cWq, cWqT, 1024, 256);
    wtrans_kernel<<<dim3(8, 32), blk, 0, stream>>>(cWk, cWkT, 1024, 256);
    wtrans_kernel<<<dim3(32, 32), blk, 0, stream>>>(cWv, cWvT, 1024, 1024);
    wtrans_kernel<<<dim3(32, 32), blk, 0, stream>>>(cWo, cWoT, 1024, 1024);
    wtrans_kernel<<<dim3(32, 64), blk, 0, stream>>>(cWg, cWgT, 2048, 1024);
    wtrans_kernel<<<dim3(32, 32), blk, 0, stream>>>(oW1, oW1T, 1024, 1024);
    wtrans_kernel<<<dim3(64, 32), blk, 0, stream>>>(oW2, oW2T, 1024, 2048);
    wtrans_kernel<<<dim3(32, 64), blk, 0, stream>>>(oW3, oW3T, 2048, 1024);
    // ---- phase 1: fused projections ----
    gemm_bf16_kernel<true,false,false><<<dim3(20, 64), blk, 0, stream>>>(
        hs_bf, 1024, wqT, 1024, bq, bk, bv, 768, 1536, nullptr, qkv_bf, 2560, 2560, 1024);
    packmask_kernel<<<16384, blk, 0, stream>>>(csm, csmb);    // hs_bf now dead
    ln_kernel<<<8192, blk, 0, stream>>>(hs, sent, ent, ln_g, ln_b, nullptr, h1_bf, 1024);
    gemm_bf16_kernel<true,false,false><<<dim3(4, 64), blk, 0, stream>>>(
        h1_bf, 1024, wq1T, 1024, bq1, bk1, nullptr, 256, BIG, nullptr, q1k1_bf, 512, 512, 1024);
    trans_kernel<<<dim3(32, 32, 8), blk, 0, stream>>>(qkv_bf, Vt, 1024, 1024, 2560, 1536);
    // ---- phase 2: attention + loss ----
    attn_mfma_kernel<<<dim3(16, 4, 8), blk, 0, stream>>>(
        qkv_bf, q1k1_bf, Vt, am, smb, ctx_bf, nump, denp);
    loss_reduce_kernel<<<1, blk, 0, stream>>>(nump, denp, out + 8388608);
    // ---- phase 3: gnn (LN writes bf16 into gc_b left half, pitch 2048) ----
    gemm_bf16_kernel<true,false,false><<<dim3(8, 64), blk, 0, stream>>>(
        ctx_bf, 1024, gWT_, 1024, gb, nullptr, nullptr, BIG, BIG, gnn_f, nullptr, 1024, 1024, 1024);
    ln_kernel<<<8192, blk, 0, stream>>>(gnn_f, nullptr, nullptr, gng, gnb,
                                        gnnout_f, gc_b, 2048);
    // ---- phase 4: cross attention + fused gate ----
    gemm_bf16_kernel<true,false,false><<<dim3(2, 64), blk, 0, stream>>>(
        gc_b, 2048, cWqT, 1024, cbq, nullptr, nullptr, BIG, BIG, nullptr, cq_b, 256, 256, 1024);
    gemm_bf16_kernel<true,false,false><<<dim3(10, 32), blk, 0, stream>>>(
        enc_bf, 1024, cWkT, 1024, cbk, cbv, nullptr, 256, BIG, nullptr, ckv_b, 1280, 1280, 1024);
    trans_kernel<<<dim3(16, 32, 8), blk, 0, stream>>>(ckv_b, cvt, 512, 1024, 1280, 256);
    cross_mfma_kernel<<<dim3(16, 4, 8), blk, 0, stream>>>(
        cq_b, ckv_b, cvt, csmb, cctx_b);
    // cWo: fp32 -> cctxo_f (pitch 1024), bf16 -> gc_b right half (pitch 2048)
    gemm_bf16_kernel<true,false,false><<<dim3(8, 64), blk, 0, stream>>>(
        cctx_b, 1024, cWoT, 1024, cbo, nullptr, nullptr, BIG, BIG, cctxo_f, gc_b + 1024, 1024, 2048, 1024);
    // fused gate: [gnnout|cctxo] (K=2048) @ cWg
    gemm_bf16_kernel<true,false,false><<<dim3(8, 64), blk, 0, stream>>>(
        gc_b, 2048, cWgT, 2048, cbg, nullptr, nullptr, BIG, BIG, gatepre_f, nullptr, 1024, 1024, 2048);
    gate_ln_kernel<<<8192, blk, 0, stream>>>(gatepre_f, cctxo_f, gnnout_f,
                                             clg, clb, nullptr, crossout_b);
    // ---- phase 5: output block ----
    gemm_bf16_kernel<true,false,false><<<dim3(8, 64), blk, 0, stream>>>(
        crossout_b, 1024, oW1T, 1024, ob1, nullptr, nullptr, BIG, BIG, t_f, nullptr, 1024, 1024, 1024);
    ln_kernel<<<8192, blk, 0, stream>>>(t_f, hs, nullptr, l1g, l1b, h_f, h_b, 1024);
    gemm_bf16_kernel<true,false,true><<<dim3(16, 64), blk, 0, stream>>>(
        h_b, 1024, oW2T, 1024, ob2, nullptr, nullptr, BIG, BIG, nullptr, h2g_b, 2048, 2048, 1024);
    gemm_bf16_kernel<true,false,false><<<dim3(8, 64), blk, 0, stream>>>(
        h2g_b, 2048, oW3T, 2048, ob3, nullptr, nullptr, BIG, BIG, h3_f, nullptr, 1024, 1024, 2048);
    ln_kernel<<<8192, blk, 0, stream>>>(h3_f, h_f, nullptr, l3g, l3b, out, nullptr, 1024);
}